// Round 2
// baseline (2467.469 us; speedup 1.0000x reference)
//
#include <hip/hip_runtime.h>
#include <hip/hip_bf16.h>
#include <math.h>

#define B_ 8
#define A_ 1024
#define NN_ 64
#define G_ 25
#define F_ 128
#define L_ 3

typedef __hip_bfloat16 bf16;

__device__ __forceinline__ float b2f(bf16 v){ return __bfloat162float(v); }
__device__ __forceinline__ float sspf(float x){
  return fmaxf(x, 0.0f) + log1pf(expf(-fabsf(x))) - 0.6931471805599453f;
}
// dual-dtype load: isbf==1 -> src is bf16, else fp32
__device__ __forceinline__ float ldsel(const void* p, long long i, int isbf){
  return isbf ? __bfloat162float(((const bf16*)p)[i]) : ((const float*)p)[i];
}

// ------------------------------------------------ dtype sniffer
// positions ~ N(0,3). If buffer is bf16, low 16 bits of each u32 word are a
// bf16 pattern -> exponent field in [118,132] nearly always. If fp32, those
// bits are uniform mantissa noise -> ~6% hit rate. 128 samples separate.
__global__ __launch_bounds__(128) void k_sniff(const unsigned int* __restrict__ raw,
                                               int* __restrict__ flag){
  __shared__ int cnt;
  if(threadIdx.x==0) cnt = 0;
  __syncthreads();
  unsigned w = raw[threadIdx.x];
  unsigned e = (w >> 7) & 0xFF;
  if(e >= 118 && e <= 132) atomicAdd(&cnt, 1);
  __syncthreads();
  if(threadIdx.x==0) *flag = (cnt >= 64) ? 1 : 0;
}

// ------------------------------------------------ generic converter -> fp32
__global__ __launch_bounds__(256) void k_conv(const void* __restrict__ src,
                                              float* __restrict__ dst, int n,
                                              const int* __restrict__ flag){
  int i = blockIdx.x*256 + threadIdx.x;
  if(i < n) dst[i] = ldsel(src, i, *flag);
}

// fw1 [L][G][F] -> transposed fp32 [L][F][G]
__global__ __launch_bounds__(256) void k_convfw1(const void* __restrict__ src,
                                                 float* __restrict__ dst,
                                                 const int* __restrict__ flag){
  int i = blockIdx.x*256 + threadIdx.x;
  if(i >= L_*G_*F_) return;
  int l = i / (G_*F_); int rem = i - l*G_*F_; int g = rem >> 7; int f = rem & 127;
  dst[l*F_*G_ + f*G_ + g] = ldsel(src, i, *flag);
}

// ------------------------------------------------ embed (from converted emb)
__global__ __launch_bounds__(256) void k_embed(const int* __restrict__ z,
                                               const float* __restrict__ emb,
                                               float* __restrict__ x){
  int i = blockIdx.x*256 + threadIdx.x;
  if(i < B_*A_*F_){
    int m = i >> 7, f = i & 127;
    x[i] = emb[z[m]*F_ + f];
  }
}

// ------------------------------------------------ distances (dual-dtype reads)
__global__ __launch_bounds__(256) void k_rdist(const void* __restrict__ pos,
                                               const void* __restrict__ cell,
                                               const void* __restrict__ celloff,
                                               const int* __restrict__ nbr,
                                               const int* __restrict__ flag,
                                               float* __restrict__ r){
  int p = blockIdx.x*256 + threadIdx.x;
  if(p >= B_*A_*NN_) return;
  int isbf = *flag;
  int m = p >> 6;
  int b = m >> 10;
  int j = nbr[p];
  long long pi = (long long)m*3, pj = (long long)(b*A_+j)*3;
  long long co = (long long)p*3, ce = (long long)b*9;
  float o0 = ldsel(celloff,co+0,isbf), o1 = ldsel(celloff,co+1,isbf), o2 = ldsel(celloff,co+2,isbf);
  float d2 = 0.0f;
  #pragma unroll
  for(int c=0;c<3;c++){
    float off = o0*ldsel(cell,ce+0*3+c,isbf) + o1*ldsel(cell,ce+1*3+c,isbf) + o2*ldsel(cell,ce+2*3+c,isbf);
    float dv = ldsel(pos,pj+c,isbf) - ldsel(pos,pi+c,isbf) + off;
    d2 += dv*dv;
  }
  r[p] = (d2 > 0.0f) ? sqrtf(d2) : 0.0f;
}

// ------------------------------------------------ y = x @ in2f_w[l] (fp32)
__global__ __launch_bounds__(128) void k_ygemm(const float* __restrict__ x,
                                               const float* __restrict__ w,
                                               float* __restrict__ y){
  __shared__ float sx[32][F_];   // 16 KB
  __shared__ float sW[32][F_];   // 16 KB
  int t = threadIdx.x;
  int row0 = blockIdx.x * 32;
  for(int i=t;i<32*F_;i+=128) ((float*)sx)[i] = x[row0*F_ + i];
  float acc[32];
  #pragma unroll
  for(int r=0;r<32;r++) acc[r] = 0.0f;
  for(int kc=0;kc<4;kc++){
    __syncthreads();
    for(int i=t;i<32*F_;i+=128) ((float*)sW)[i] = w[kc*32*F_ + i];
    __syncthreads();
    for(int k=0;k<32;k++){
      float wv = sW[k][t];
      #pragma unroll
      for(int r=0;r<32;r++) acc[r] += sx[r][kc*32 + k]*wv;
    }
  }
  #pragma unroll
  for(int r=0;r<32;r++) y[(row0+r)*F_ + t] = acc[r];
}

// ------------------------------------------------ fused per-atom layer (fp32)
__global__ __launch_bounds__(256) void k_atom(
    const float* __restrict__ xws, const float* __restrict__ yws,
    const float* __restrict__ rws,
    const int*  __restrict__ nbrg, const void* __restrict__ maskg,
    const float* __restrict__ fw1t, const float* __restrict__ fb1g,
    const float* __restrict__ fw2g, const float* __restrict__ fb2g,
    const float* __restrict__ f2owg, const float* __restrict__ f2obg,
    const float* __restrict__ dwg,  const float* __restrict__ dbg,
    const int* __restrict__ flag,
    float* __restrict__ xout, void* __restrict__ dout,
    int layer, int write_out)
{
  __shared__ float s_fij[NN_][G_+1];   // 6656 B
  __shared__ float s_h1[NN_][F_];      // 32768 B
  __shared__ float s_fw2c[32][F_];     // 16384 B
  __shared__ float s_fb1[F_], s_fb2[F_], s_fb3[F_], s_fb4[F_];
  __shared__ float s_r[NN_]; __shared__ int s_nbr[NN_]; __shared__ float s_mask[NN_];
  __shared__ float s_v[F_];  __shared__ float s_t1[F_];
  __shared__ float s_part[2][F_];

  int t = threadIdx.x;
  int m = blockIdx.x;
  int b = m >> 10;
  int f = t & 127, nh = t >> 7;
  int isbf = *flag;

  if(t < F_){
    s_fb1[t] = fb1g[layer*F_+t];
    s_fb2[t] = fb2g[layer*F_+t];
    s_fb3[t] = f2obg[layer*F_+t];
    s_fb4[t] = dbg[layer*F_+t];
  }
  if(t < NN_){
    s_r[t]    = rws[m*NN_+t];
    s_nbr[t]  = nbrg[m*NN_+t];
    s_mask[t] = ldsel(maskg, m*NN_+t, isbf);
  }
  __syncthreads();

  // Gaussian smearing [64][25]
  const float width = 5.0f/24.0f;
  const float coeff = -0.5f/(width*width);
  for(int i=t;i<NN_*G_;i+=256){
    int n = i/G_, g = i - n*G_;
    float d = s_r[n] - (float)g*width;
    s_fij[n][g] = expf(coeff*d*d);
  }
  __syncthreads();

  // h1 = ssp(f_ij @ fw1 + fb1): thread (f, nh) does rows nh*32 .. +32
  {
    float wf[G_];
    const float* wcol = fw1t + layer*F_*G_ + f*G_;
    #pragma unroll
    for(int k=0;k<G_;k++) wf[k] = wcol[k];
    float bias = s_fb1[f];
    for(int i=0;i<32;i++){
      int n = nh*32 + i;
      float acc = bias;
      #pragma unroll
      for(int k=0;k<G_;k++) acc += s_fij[n][k]*wf[k];
      s_h1[n][f] = sspf(acc);
    }
  }

  // W = h1 @ fw2 + fb2, K-chunked 32 at a time; accw[i] = W[nh*32+i][f]
  const float* fw2l = fw2g + layer*F_*F_;
  float accw[32];
  float bias2 = s_fb2[f];
  #pragma unroll
  for(int i=0;i<32;i++) accw[i] = bias2;
  for(int kc=0;kc<4;kc++){
    for(int i=t;i<32*F_;i+=256) ((float*)s_fw2c)[i] = fw2l[kc*32*F_ + i];
    __syncthreads();
    for(int k=0;k<32;k++){
      float w = s_fw2c[k][f];
      int kk = kc*32 + k;
      #pragma unroll
      for(int i=0;i<32;i++)
        accw[i] += s_h1[nh*32+i][kk] * w;
    }
    __syncthreads();
  }

  // v[f] = sum_n W[n][f] * y[nbr[n]][f] * mask[n]   (yj straight from global/L2)
  float accv = 0.0f;
  #pragma unroll
  for(int i=0;i<32;i++){
    int n = nh*32 + i;
    accv += accw[i] * yws[(b*A_ + s_nbr[n])*F_ + f] * s_mask[n];
  }
  s_part[nh][f] = accv;
  __syncthreads();
  if(t < F_) s_v[t] = s_part[0][t] + s_part[1][t];
  __syncthreads();

  // t1 = ssp(v @ f2out_w + f2out_b)
  {
    const float* wg = f2owg + layer*F_*F_;
    float acc = 0.0f;
    for(int k=nh*64;k<nh*64+64;k++) acc += s_v[k]*wg[k*F_+f];
    s_part[nh][f] = acc;
  }
  __syncthreads();
  if(t < F_) s_t1[t] = sspf(s_part[0][t] + s_part[1][t] + s_fb3[t]);
  __syncthreads();

  // out = t1 @ dense_w + dense_b ; x += out
  {
    const float* wg = dwg + layer*F_*F_;
    float acc = 0.0f;
    for(int k=nh*64;k<nh*64+64;k++) acc += s_t1[k]*wg[k*F_+f];
    s_part[nh][f] = acc;
  }
  __syncthreads();
  if(t < F_){
    float xn = xws[m*F_+t] + s_part[0][t] + s_part[1][t] + s_fb4[t];
    xout[m*F_+t] = xn;
    if(write_out){
      if(isbf) ((bf16*)dout)[m*F_+t] = __float2bfloat16(xn);
      else     ((float*)dout)[m*F_+t] = xn;
    }
  }
}

// ------------------------------------------------ launch
extern "C" void kernel_launch(void* const* d_in, const int* in_sizes, int n_in,
                              void* d_out, int out_size, void* d_ws, size_t ws_size,
                              hipStream_t stream){
  const int*  z       = (const int*)d_in[0];
  const void* pos     = d_in[1];
  const void* cell    = d_in[2];
  const void* celloff = d_in[3];
  const int*  nbr     = (const int*)d_in[4];
  const void* mask    = d_in[5];
  const void* emb     = d_in[6];
  const void* fw1     = d_in[7];
  const void* fb1     = d_in[8];
  const void* fw2     = d_in[9];
  const void* fb2     = d_in[10];
  const void* in2f    = d_in[11];
  const void* f2ow    = d_in[12];
  const void* f2ob    = d_in[13];
  const void* dw      = d_in[14];
  const void* db      = d_in[15];

  int*   flag   = (int*)d_ws;
  float* base   = (float*)d_ws;
  float* c_emb  = base + 16;            // 12800
  float* c_fw1t = c_emb + 12800;        // 9600  [L][F][G]
  float* c_fb1  = c_fw1t + 9600;        // 384
  float* c_fw2  = c_fb1 + 384;          // 49152
  float* c_fb2  = c_fw2 + 49152;        // 384
  float* c_in2f = c_fb2 + 384;          // 49152
  float* c_f2ow = c_in2f + 49152;       // 49152
  float* c_f2ob = c_f2ow + 49152;       // 384
  float* c_dw   = c_f2ob + 384;         // 49152
  float* c_db   = c_dw + 49152;         // 384
  float* xws    = c_db + 384;           // 1048576
  float* yws    = xws + B_*A_*F_;       // 1048576
  float* rws    = yws + B_*A_*F_;       // 524288   (total ~11.4 MB)

  k_sniff<<<1, 128, 0, stream>>>((const unsigned int*)pos, flag);

  #define CONV(src, dst, n) k_conv<<<((n)+255)/256, 256, 0, stream>>>(src, dst, n, flag)
  CONV(emb,  c_emb,  12800);
  CONV(fb1,  c_fb1,  384);
  CONV(fw2,  c_fw2,  49152);
  CONV(fb2,  c_fb2,  384);
  CONV(in2f, c_in2f, 49152);
  CONV(f2ow, c_f2ow, 49152);
  CONV(f2ob, c_f2ob, 384);
  CONV(dw,   c_dw,   49152);
  CONV(db,   c_db,   384);
  #undef CONV
  k_convfw1<<<(L_*G_*F_+255)/256, 256, 0, stream>>>(fw1, c_fw1t, flag);

  k_embed<<<(B_*A_*F_ + 255)/256, 256, 0, stream>>>(z, c_emb, xws);
  k_rdist<<<(B_*A_*NN_ + 255)/256, 256, 0, stream>>>(pos, cell, celloff, nbr, flag, rws);

  for(int l=0;l<L_;l++){
    k_ygemm<<<(B_*A_)/32, 128, 0, stream>>>(xws, c_in2f + l*F_*F_, yws);
    k_atom<<<B_*A_, 256, 0, stream>>>(xws, yws, rws, nbr, mask,
                                      c_fw1t, c_fb1, c_fw2, c_fb2,
                                      c_f2ow, c_f2ob, c_dw, c_db, flag,
                                      xws, d_out, l, (l==L_-1) ? 1 : 0);
  }
}

// Round 3
// 555.646 us; speedup vs baseline: 4.4407x; 4.4407x over previous
//
#include <hip/hip_runtime.h>
#include <hip/hip_bf16.h>
#include <math.h>

#define B_ 8
#define A_ 1024
#define NN_ 64
#define G_ 25
#define F_ 128
#define L_ 3

typedef __hip_bfloat16 bf16;
typedef __bf16 bf16x8 __attribute__((ext_vector_type(8)));
typedef float floatx4 __attribute__((ext_vector_type(4)));

__device__ __forceinline__ float sspf(float x){
  return fmaxf(x, 0.0f) + log1pf(expf(-fabsf(x))) - 0.6931471805599453f;
}
// fast shifted softplus: ln(0.5 e^x + 0.5); args here are O(1) -> no overflow
__device__ __forceinline__ float sspfast(float x){
  return __logf(0.5f*__expf(x) + 0.5f);
}
__device__ __forceinline__ float ldsel(const void* p, long long i, int isbf){
  return isbf ? __bfloat162float(((const bf16*)p)[i]) : ((const float*)p)[i];
}

// ------------------------------------------------ dtype sniffer (see r2 notes)
__global__ __launch_bounds__(128) void k_sniff(const unsigned int* __restrict__ raw,
                                               int* __restrict__ flag){
  __shared__ int cnt;
  if(threadIdx.x==0) cnt = 0;
  __syncthreads();
  unsigned w = raw[threadIdx.x];
  unsigned e = (w >> 7) & 0xFF;
  if(e >= 118 && e <= 132) atomicAdd(&cnt, 1);
  __syncthreads();
  if(threadIdx.x==0) *flag = (cnt >= 64) ? 1 : 0;
}

// ------------------------------------------------ generic converter -> fp32
__global__ __launch_bounds__(256) void k_conv(const void* __restrict__ src,
                                              float* __restrict__ dst, int n,
                                              const int* __restrict__ flag){
  int i = blockIdx.x*256 + threadIdx.x;
  if(i < n) dst[i] = ldsel(src, i, *flag);
}

// fw1 [L][25][128] -> bf16 [L][128][32] (f-major, K padded 25->32 with zeros)
__global__ __launch_bounds__(256) void k_convfw1t(const void* __restrict__ src,
                                                  __bf16* __restrict__ dst,
                                                  const int* __restrict__ flag){
  int i = blockIdx.x*256 + threadIdx.x;
  if(i >= L_*F_*32) return;
  int l = i >> 12; int rem = i & 4095; int f = rem >> 5; int k = rem & 31;
  float v = (k < G_) ? ldsel(src, (long long)l*G_*F_ + k*F_ + f, *flag) : 0.0f;
  dst[i] = (__bf16)v;
}

// fw2 [L][128][128] -> bf16 [L][128][128] transposed to f-major ([f][k])
__global__ __launch_bounds__(256) void k_convfw2t(const void* __restrict__ src,
                                                  __bf16* __restrict__ dst,
                                                  const int* __restrict__ flag){
  int i = blockIdx.x*256 + threadIdx.x;
  if(i >= L_*F_*F_) return;
  int l = i >> 14; int rem = i & 16383; int f = rem >> 7; int k = rem & 127;
  dst[i] = (__bf16)ldsel(src, (long long)l*F_*F_ + k*F_ + f, *flag);
}

// ------------------------------------------------ embed
__global__ __launch_bounds__(256) void k_embed(const int* __restrict__ z,
                                               const float* __restrict__ emb,
                                               float* __restrict__ x){
  int i = blockIdx.x*256 + threadIdx.x;
  if(i < B_*A_*F_){
    int m = i >> 7, f = i & 127;
    x[i] = emb[z[m]*F_ + f];
  }
}

// ------------------------------------------------ distances
__global__ __launch_bounds__(256) void k_rdist(const void* __restrict__ pos,
                                               const void* __restrict__ cell,
                                               const void* __restrict__ celloff,
                                               const int* __restrict__ nbr,
                                               const int* __restrict__ flag,
                                               float* __restrict__ r){
  int p = blockIdx.x*256 + threadIdx.x;
  if(p >= B_*A_*NN_) return;
  int isbf = *flag;
  int m = p >> 6;
  int b = m >> 10;
  int j = nbr[p];
  long long pi = (long long)m*3, pj = (long long)(b*A_+j)*3;
  long long co = (long long)p*3, ce = (long long)b*9;
  float o0 = ldsel(celloff,co+0,isbf), o1 = ldsel(celloff,co+1,isbf), o2 = ldsel(celloff,co+2,isbf);
  float d2 = 0.0f;
  #pragma unroll
  for(int c=0;c<3;c++){
    float off = o0*ldsel(cell,ce+0*3+c,isbf) + o1*ldsel(cell,ce+1*3+c,isbf) + o2*ldsel(cell,ce+2*3+c,isbf);
    float dv = ldsel(pos,pj+c,isbf) - ldsel(pos,pi+c,isbf) + off;
    d2 += dv*dv;
  }
  r[p] = (d2 > 0.0f) ? sqrtf(d2) : 0.0f;
}

// ------------------------------------------------ y = x @ in2f_w[l] (fp32)
__global__ __launch_bounds__(128) void k_ygemm(const float* __restrict__ x,
                                               const float* __restrict__ w,
                                               float* __restrict__ y){
  __shared__ float sx[32][F_];
  __shared__ float sW[32][F_];
  int t = threadIdx.x;
  int row0 = blockIdx.x * 32;
  for(int i=t;i<32*F_;i+=128) ((float*)sx)[i] = x[row0*F_ + i];
  float acc[32];
  #pragma unroll
  for(int r=0;r<32;r++) acc[r] = 0.0f;
  for(int kc=0;kc<4;kc++){
    __syncthreads();
    for(int i=t;i<32*F_;i+=128) ((float*)sW)[i] = w[kc*32*F_ + i];
    __syncthreads();
    for(int k=0;k<32;k++){
      float wv = sW[k][t];
      #pragma unroll
      for(int r=0;r<32;r++) acc[r] += sx[r][kc*32 + k]*wv;
    }
  }
  #pragma unroll
  for(int r=0;r<32;r++) y[(row0+r)*F_ + t] = acc[r];
}

// ------------------------------------------------ fused per-atom layer, MFMA
// LDS carve (40192 B total, all sub-arrays 16B-aligned):
//   s_h1  bf16 [64][136]  @ 0      (17408 B)  A-operand for GEMM2
//   s_yj  bf16 [64][132]  @ 17408  (16896 B)  gathered y[nbr]*mask
//   s_fij bf16 [64][40]   @ 34304  ( 5120 B)  A-operand GEMM1 (K padded to 32)
//     (overlaid after GEMM1 by: s_v @34304, s_t1 @34816, s_part @35328)
//   s_r f32[64] @39424, s_nbr i32[64] @39680, s_mask f32[64] @39936
// 40192 x 4 blocks = 157 KB < 160 KB -> 4 blocks/CU.
__global__ __launch_bounds__(256, 4) void k_atom(
    const float* __restrict__ xws, const float* __restrict__ yws,
    const float* __restrict__ rws,
    const int*  __restrict__ nbrg, const void* __restrict__ maskg,
    const __bf16* __restrict__ fw1tb, const float* __restrict__ fb1g,
    const __bf16* __restrict__ fw2tb, const float* __restrict__ fb2g,
    const float* __restrict__ f2owg, const float* __restrict__ f2obg,
    const float* __restrict__ dwg,  const float* __restrict__ dbg,
    const int* __restrict__ flag,
    float* __restrict__ xout, void* __restrict__ dout,
    int layer, int write_out)
{
  __shared__ __align__(16) unsigned char smem[40192];
  __bf16* s_h1  = (__bf16*)smem;                 // stride 136
  __bf16* s_yj  = (__bf16*)(smem + 17408);       // stride 132
  __bf16* s_fij = (__bf16*)(smem + 34304);       // stride 40
  float*  s_v    = (float*)(smem + 34304);
  float*  s_t1   = (float*)(smem + 34816);
  float*  s_part = (float*)(smem + 35328);       // [2][128]
  float*  s_r    = (float*)(smem + 39424);
  int*    s_nbr  = (int*)  (smem + 39680);
  float*  s_mask = (float*)(smem + 39936);

  int t = threadIdx.x;
  int m = blockIdx.x;
  int b = m >> 10;
  int lane = t & 63, wid = t >> 6;
  int c = lane & 15, quad = lane >> 4;
  int isbf = *flag;

  if(t < NN_){
    s_r[t]    = rws[m*NN_+t];
    s_nbr[t]  = nbrg[m*NN_+t];
    s_mask[t] = ldsel(maskg, m*NN_+t, isbf);
  }
  __syncthreads();

  // Gaussian smearing -> bf16 A-layout [64][40] (cols 25..39 zero)
  const float width = 5.0f/24.0f;
  const float coeff = -0.5f/(width*width);
  for(int i=t;i<NN_*40;i+=256){
    int n = i/40, g = i - n*40;
    float val = 0.0f;
    if(g < G_){
      float d = s_r[n] - (float)g*width;
      val = __expf(coeff*d*d);
    }
    s_fij[i] = (__bf16)val;
  }
  // gather yj = y[nbr]*mask -> bf16 [64][132]
  {
    int n = t >> 2, f0 = (t & 3) * 32;
    const float* src = yws + ((long long)(b*A_ + s_nbr[n]))*F_ + f0;
    float msk = s_mask[n];
    __bf16* dst = s_yj + n*132 + f0;
    #pragma unroll
    for(int j=0;j<8;j++){
      float4 v4 = ((const float4*)src)[j];
      dst[j*4+0] = (__bf16)(v4.x*msk);
      dst[j*4+1] = (__bf16)(v4.y*msk);
      dst[j*4+2] = (__bf16)(v4.z*msk);
      dst[j*4+3] = (__bf16)(v4.w*msk);
    }
  }
  __syncthreads();

  int ft0 = wid, ft1 = wid + 4;
  // ---------------- GEMM1: h1 = ssp(fij @ fw1 + fb1), K=32 (padded)
  {
    const __bf16* fw1l = fw1tb + layer*F_*32;
    bf16x8 b0 = *(const bf16x8*)(fw1l + (ft0*16 + c)*32 + quad*8);
    bf16x8 b1 = *(const bf16x8*)(fw1l + (ft1*16 + c)*32 + quad*8);
    float bias0 = fb1g[layer*F_ + ft0*16 + c];
    float bias1 = fb1g[layer*F_ + ft1*16 + c];
    #pragma unroll
    for(int mt=0; mt<4; mt++){
      bf16x8 a = *(const bf16x8*)(s_fij + (mt*16 + c)*40 + quad*8);
      floatx4 z = {0.f,0.f,0.f,0.f};
      floatx4 acc0 = __builtin_amdgcn_mfma_f32_16x16x32_bf16(a, b0, z, 0,0,0);
      floatx4 acc1 = __builtin_amdgcn_mfma_f32_16x16x32_bf16(a, b1, z, 0,0,0);
      #pragma unroll
      for(int r=0;r<4;r++){
        int n = mt*16 + quad*4 + r;
        s_h1[n*136 + ft0*16 + c] = (__bf16)sspfast(acc0[r] + bias0);
        s_h1[n*136 + ft1*16 + c] = (__bf16)sspfast(acc1[r] + bias1);
      }
    }
  }
  __syncthreads();

  // ---------------- GEMM2: W = h1 @ fw2 + fb2, fused v = sum_n W .* yj
  {
    const __bf16* fw2l = fw2tb + layer*F_*F_;
    bf16x8 bw0[4], bw1[4];
    #pragma unroll
    for(int kt=0;kt<4;kt++){
      bw0[kt] = *(const bf16x8*)(fw2l + (ft0*16 + c)*F_ + kt*32 + quad*8);
      bw1[kt] = *(const bf16x8*)(fw2l + (ft1*16 + c)*F_ + kt*32 + quad*8);
    }
    float fb2_0 = fb2g[layer*F_ + ft0*16 + c];
    float fb2_1 = fb2g[layer*F_ + ft1*16 + c];
    float vp0 = 0.0f, vp1 = 0.0f;
    #pragma unroll
    for(int mt=0; mt<4; mt++){
      floatx4 acc0 = {0.f,0.f,0.f,0.f};
      floatx4 acc1 = {0.f,0.f,0.f,0.f};
      #pragma unroll
      for(int kt=0;kt<4;kt++){
        bf16x8 a = *(const bf16x8*)(s_h1 + (mt*16 + c)*136 + kt*32 + quad*8);
        acc0 = __builtin_amdgcn_mfma_f32_16x16x32_bf16(a, bw0[kt], acc0, 0,0,0);
        acc1 = __builtin_amdgcn_mfma_f32_16x16x32_bf16(a, bw1[kt], acc1, 0,0,0);
      }
      #pragma unroll
      for(int r=0;r<4;r++){
        int n = mt*16 + quad*4 + r;
        vp0 += (acc0[r] + fb2_0) * (float)s_yj[n*132 + ft0*16 + c];
        vp1 += (acc1[r] + fb2_1) * (float)s_yj[n*132 + ft1*16 + c];
      }
    }
    vp0 += __shfl_xor(vp0, 16); vp0 += __shfl_xor(vp0, 32);
    vp1 += __shfl_xor(vp1, 16); vp1 += __shfl_xor(vp1, 32);
    if(quad == 0){
      s_v[ft0*16 + c] = vp0;
      s_v[ft1*16 + c] = vp1;
    }
  }
  __syncthreads();

  // ---------------- epilogue: two 128x128 matvecs + residual
  int f = t & 127, nh = t >> 7;
  {
    const float* wg = f2owg + layer*F_*F_;
    float acc = 0.0f;
    for(int k=nh*64;k<nh*64+64;k++) acc += s_v[k]*wg[k*F_+f];
    s_part[nh*128+f] = acc;
  }
  __syncthreads();
  if(t < F_) s_t1[t] = sspf(s_part[t] + s_part[128+t] + f2obg[layer*F_+t]);
  __syncthreads();
  {
    const float* wg = dwg + layer*F_*F_;
    float acc = 0.0f;
    for(int k=nh*64;k<nh*64+64;k++) acc += s_t1[k]*wg[k*F_+f];
    s_part[nh*128+f] = acc;
  }
  __syncthreads();
  if(t < F_){
    float xn = xws[m*F_+t] + s_part[t] + s_part[128+t] + dbg[layer*F_+t];
    xout[m*F_+t] = xn;
    if(write_out){
      if(isbf) ((bf16*)dout)[m*F_+t] = __float2bfloat16(xn);
      else     ((float*)dout)[m*F_+t] = xn;
    }
  }
}

// ------------------------------------------------ launch
extern "C" void kernel_launch(void* const* d_in, const int* in_sizes, int n_in,
                              void* d_out, int out_size, void* d_ws, size_t ws_size,
                              hipStream_t stream){
  const int*  z       = (const int*)d_in[0];
  const void* pos     = d_in[1];
  const void* cell    = d_in[2];
  const void* celloff = d_in[3];
  const int*  nbr     = (const int*)d_in[4];
  const void* mask    = d_in[5];
  const void* emb     = d_in[6];
  const void* fw1     = d_in[7];
  const void* fb1     = d_in[8];
  const void* fw2     = d_in[9];
  const void* fb2     = d_in[10];
  const void* in2f    = d_in[11];
  const void* f2ow    = d_in[12];
  const void* f2ob    = d_in[13];
  const void* dw      = d_in[14];
  const void* db      = d_in[15];

  int*   flag    = (int*)d_ws;
  float* base    = (float*)d_ws;
  float* c_emb   = base + 16;             // 12800
  float* c_fb1   = c_emb + 12800;         // 384
  float* c_fb2   = c_fb1 + 384;           // 384
  float* c_in2f  = c_fb2 + 384;           // 49152
  float* c_f2ow  = c_in2f + 49152;        // 49152
  float* c_f2ob  = c_f2ow + 49152;        // 384
  float* c_dw    = c_f2ob + 384;          // 49152
  float* c_db    = c_dw + 49152;          // 384
  __bf16* c_fw1tb = (__bf16*)(c_db + 384);       // L*128*32  bf16 = 6144 floats
  __bf16* c_fw2tb = (__bf16*)(c_db + 384 + 6144);// L*128*128 bf16 = 24576 floats
  float* xws     = c_db + 384 + 6144 + 24576;    // 1048576
  float* yws     = xws + B_*A_*F_;               // 1048576
  float* rws     = yws + B_*A_*F_;               // 524288

  k_sniff<<<1, 128, 0, stream>>>((const unsigned int*)pos, flag);

  #define CONV(src, dst, n) k_conv<<<((n)+255)/256, 256, 0, stream>>>(src, dst, n, flag)
  CONV(emb,  c_emb,  12800);
  CONV(fb1,  c_fb1,  384);
  CONV(fb2,  c_fb2,  384);
  CONV(in2f, c_in2f, 49152);
  CONV(f2ow, c_f2ow, 49152);
  CONV(f2ob, c_f2ob, 384);
  CONV(dw,   c_dw,   49152);
  CONV(db,   c_db,   384);
  #undef CONV
  k_convfw1t<<<(L_*F_*32+255)/256, 256, 0, stream>>>(fw1, c_fw1tb, flag);
  k_convfw2t<<<(L_*F_*F_+255)/256, 256, 0, stream>>>(fw2, c_fw2tb, flag);

  k_embed<<<(B_*A_*F_ + 255)/256, 256, 0, stream>>>(z, c_emb, xws);
  k_rdist<<<(B_*A_*NN_ + 255)/256, 256, 0, stream>>>(pos, cell, celloff, nbr, flag, rws);

  for(int l=0;l<L_;l++){
    k_ygemm<<<(B_*A_)/32, 128, 0, stream>>>(xws, c_in2f + l*F_*F_, yws);
    k_atom<<<B_*A_, 256, 0, stream>>>(xws, yws, rws, nbr, mask,
                                      c_fw1tb, c_fb1, c_fw2tb, c_fb2,
                                      c_f2ow, c_f2ob, c_dw, c_db, flag,
                                      xws, d_out, l, (l==L_-1) ? 1 : 0);
  }
}

// Round 4
// 339.168 us; speedup vs baseline: 7.2751x; 1.6383x over previous
//
#include <hip/hip_runtime.h>
#include <hip/hip_bf16.h>
#include <math.h>

#define B_ 8
#define A_ 1024
#define NN_ 64
#define G_ 25
#define F_ 128
#define L_ 3

typedef __hip_bfloat16 bf16;
typedef __bf16 bf16x8 __attribute__((ext_vector_type(8)));
typedef float floatx4 __attribute__((ext_vector_type(4)));

__device__ __forceinline__ float sspfast(float x){
  // shifted softplus ln(0.5 e^x + 0.5); args here are O(1) -> no overflow
  return __logf(0.5f*__expf(x) + 0.5f);
}
__device__ __forceinline__ float ldsel(const void* p, long long i, int isbf){
  return isbf ? __bfloat162float(((const bf16*)p)[i]) : ((const float*)p)[i];
}

// ------------------------------------------------ dtype sniffer (see r2 notes)
__global__ __launch_bounds__(128) void k_sniff(const unsigned int* __restrict__ raw,
                                               int* __restrict__ flag){
  __shared__ int cnt;
  if(threadIdx.x==0) cnt = 0;
  __syncthreads();
  unsigned w = raw[threadIdx.x];
  unsigned e = (w >> 7) & 0xFF;
  if(e >= 118 && e <= 132) atomicAdd(&cnt, 1);
  __syncthreads();
  if(threadIdx.x==0) *flag = (cnt >= 64) ? 1 : 0;
}

// ------------------------------------------------ all weight conversions, one kernel
// regions (element index space):
//   [0,12800)        emb -> fp32
//   [12800,13184)    fb1 -> fp32
//   [13184,13568)    fb2 -> fp32
//   [13568,13952)    f2ob -> fp32
//   [13952,14336)    db  -> fp32
//   [14336,26624)    fw1 [L][25][128] -> bf16 [L][128][32] (pad K 25->32)
//   [26624,223232)   fw2/f2ow/dw/in2f [L][128][128] -> bf16 f-major [L][f][k]
__global__ __launch_bounds__(256) void k_prep(
    const void* emb, const void* fb1, const void* fb2, const void* f2ob,
    const void* db,  const void* fw1, const void* fw2, const void* f2ow,
    const void* dw,  const void* in2f,
    float* c_emb, float* c_fb1, float* c_fb2, float* c_f2ob, float* c_db,
    __bf16* fw1tb, __bf16* fw2tb, __bf16* f2owtb, __bf16* dwtb, __bf16* in2ftb,
    const int* __restrict__ flag)
{
  int idx = blockIdx.x*256 + threadIdx.x;
  if(idx >= 223232) return;
  int isbf = *flag;
  if(idx < 12800){ c_emb[idx] = ldsel(emb, idx, isbf); return; }
  if(idx < 13184){ c_fb1[idx-12800] = ldsel(fb1, idx-12800, isbf); return; }
  if(idx < 13568){ c_fb2[idx-13184] = ldsel(fb2, idx-13184, isbf); return; }
  if(idx < 13952){ c_f2ob[idx-13568] = ldsel(f2ob, idx-13568, isbf); return; }
  if(idx < 14336){ c_db[idx-13952] = ldsel(db, idx-13952, isbf); return; }
  if(idx < 26624){
    int i = idx - 14336;
    int l = i >> 12; int rem = i & 4095; int f = rem >> 5; int k = rem & 31;
    float v = (k < G_) ? ldsel(fw1, (long long)l*G_*F_ + k*F_ + f, isbf) : 0.0f;
    fw1tb[i] = (__bf16)v;
    return;
  }
  {
    int i = idx - 26624;
    int which = i / 49152; int r = i - which*49152;
    int l = r >> 14; int rem = r & 16383; int f = rem >> 7; int k = rem & 127;
    const void* src = (which==0) ? fw2 : (which==1) ? f2ow : (which==2) ? dw : in2f;
    __bf16* dst = (which==0) ? fw2tb : (which==1) ? f2owtb : (which==2) ? dwtb : in2ftb;
    dst[r] = (__bf16)ldsel(src, (long long)l*F_*F_ + k*F_ + f, isbf);
  }
}

// ------------------------------------------------ embed
__global__ __launch_bounds__(256) void k_embed(const int* __restrict__ z,
                                               const float* __restrict__ emb,
                                               float* __restrict__ x){
  int i = blockIdx.x*256 + threadIdx.x;
  if(i < B_*A_*F_){
    int m = i >> 7, f = i & 127;
    x[i] = emb[z[m]*F_ + f];
  }
}

// ------------------------------------------------ distances
__global__ __launch_bounds__(256) void k_rdist(const void* __restrict__ pos,
                                               const void* __restrict__ cell,
                                               const void* __restrict__ celloff,
                                               const int* __restrict__ nbr,
                                               const int* __restrict__ flag,
                                               float* __restrict__ r){
  int p = blockIdx.x*256 + threadIdx.x;
  if(p >= B_*A_*NN_) return;
  int isbf = *flag;
  int m = p >> 6;
  int b = m >> 10;
  int j = nbr[p];
  long long pi = (long long)m*3, pj = (long long)(b*A_+j)*3;
  long long co = (long long)p*3, ce = (long long)b*9;
  float o0 = ldsel(celloff,co+0,isbf), o1 = ldsel(celloff,co+1,isbf), o2 = ldsel(celloff,co+2,isbf);
  float d2 = 0.0f;
  #pragma unroll
  for(int c=0;c<3;c++){
    float off = o0*ldsel(cell,ce+0*3+c,isbf) + o1*ldsel(cell,ce+1*3+c,isbf) + o2*ldsel(cell,ce+2*3+c,isbf);
    float dv = ldsel(pos,pj+c,isbf) - ldsel(pos,pi+c,isbf) + off;
    d2 += dv*dv;
  }
  r[p] = (d2 > 0.0f) ? sqrtf(d2) : 0.0f;
}

// ------------------------------------------------ y = x @ in2f_w[0]  (MFMA)
__global__ __launch_bounds__(256, 4) void k_ygemm(const float* __restrict__ xws,
                                                  const __bf16* __restrict__ wtb,
                                                  float* __restrict__ yws){
  __shared__ __align__(16) __bf16 s_a[64*136];
  int t = threadIdx.x;
  int row0 = blockIdx.x*64;
  int lane = t & 63, wid = t >> 6, c = lane & 15, quad = lane >> 4;
  int ft0 = wid, ft1 = wid + 4;
  #pragma unroll
  for(int i=0;i<4;i++){
    int ch = t + i*256;            // 1024 chunks of 8
    int row = ch >> 4, col8 = ch & 15;
    const float* src = xws + (long long)(row0+row)*F_ + col8*8;
    float4 a4 = ((const float4*)src)[0];
    float4 b4 = ((const float4*)src)[1];
    bf16x8 v = {(__bf16)a4.x,(__bf16)a4.y,(__bf16)a4.z,(__bf16)a4.w,
                (__bf16)b4.x,(__bf16)b4.y,(__bf16)b4.z,(__bf16)b4.w};
    *(bf16x8*)(s_a + row*136 + col8*8) = v;
  }
  __syncthreads();
  bf16x8 bw0[4], bw1[4];
  #pragma unroll
  for(int kt=0;kt<4;kt++){
    bw0[kt] = *(const bf16x8*)(wtb + (ft0*16 + c)*F_ + kt*32 + quad*8);
    bw1[kt] = *(const bf16x8*)(wtb + (ft1*16 + c)*F_ + kt*32 + quad*8);
  }
  #pragma unroll
  for(int mt=0; mt<4; mt++){
    floatx4 acc0 = {0.f,0.f,0.f,0.f};
    floatx4 acc1 = {0.f,0.f,0.f,0.f};
    #pragma unroll
    for(int kt=0;kt<4;kt++){
      bf16x8 a = *(const bf16x8*)(s_a + (mt*16 + c)*136 + kt*32 + quad*8);
      acc0 = __builtin_amdgcn_mfma_f32_16x16x32_bf16(a, bw0[kt], acc0, 0,0,0);
      acc1 = __builtin_amdgcn_mfma_f32_16x16x32_bf16(a, bw1[kt], acc1, 0,0,0);
    }
    #pragma unroll
    for(int r=0;r<4;r++){
      int n = mt*16 + quad*4 + r;
      yws[(long long)(row0+n)*F_ + ft0*16 + c] = acc0[r];
      yws[(long long)(row0+n)*F_ + ft1*16 + c] = acc1[r];
    }
  }
}

// ------------------------------------------------ per-atom: smear -> GEMM1 -> GEMM2 .* yj -> v
__global__ __launch_bounds__(256, 4) void k_atom(
    const float* __restrict__ yws, const float* __restrict__ rws,
    const int*  __restrict__ nbrg, const void* __restrict__ maskg,
    const __bf16* __restrict__ fw1tb, const float* __restrict__ fb1g,
    const __bf16* __restrict__ fw2tb, const float* __restrict__ fb2g,
    const int* __restrict__ flag,
    __bf16* __restrict__ vwsb, int layer)
{
  __shared__ __align__(16) unsigned char smem[24064];
  __bf16* s_h1   = (__bf16*)smem;             // [64][136] 17408 B
  __bf16* s_fij  = (__bf16*)(smem + 17408);   // [64][40]   5120 B
  float*  s_r    = (float*)(smem + 22528);
  int*    s_nbr  = (int*)  (smem + 22784);
  float*  s_mask = (float*)(smem + 23040);

  int t = threadIdx.x, m = blockIdx.x, b = m >> 10;
  int lane = t & 63, wid = t >> 6, c = lane & 15, quad = lane >> 4;
  int isbf = *flag;

  if(t < NN_){
    s_r[t]    = rws[m*NN_+t];
    s_nbr[t]  = nbrg[m*NN_+t];
    s_mask[t] = ldsel(maskg, m*NN_+t, isbf);
  }
  __syncthreads();

  // Gaussian smearing -> bf16 A-layout [64][40] (cols 25..39 zero)
  const float width = 5.0f/24.0f;
  const float coeff = -0.5f/(width*width);
  for(int i=t;i<NN_*40;i+=256){
    int n = i/40, g = i - n*40;
    float val = 0.0f;
    if(g < G_){
      float d = s_r[n] - (float)g*width;
      val = __expf(coeff*d*d);
    }
    s_fij[i] = (__bf16)val;
  }
  __syncthreads();

  int ft0 = wid, ft1 = wid + 4;
  // GEMM1: h1 = ssp(fij @ fw1 + fb1), K=32 padded
  {
    const __bf16* fw1l = fw1tb + layer*F_*32;
    bf16x8 b0 = *(const bf16x8*)(fw1l + (ft0*16 + c)*32 + quad*8);
    bf16x8 b1 = *(const bf16x8*)(fw1l + (ft1*16 + c)*32 + quad*8);
    float bias0 = fb1g[layer*F_ + ft0*16 + c];
    float bias1 = fb1g[layer*F_ + ft1*16 + c];
    #pragma unroll
    for(int mt=0; mt<4; mt++){
      bf16x8 a = *(const bf16x8*)(s_fij + (mt*16 + c)*40 + quad*8);
      floatx4 z = {0.f,0.f,0.f,0.f};
      floatx4 acc0 = __builtin_amdgcn_mfma_f32_16x16x32_bf16(a, b0, z, 0,0,0);
      floatx4 acc1 = __builtin_amdgcn_mfma_f32_16x16x32_bf16(a, b1, z, 0,0,0);
      #pragma unroll
      for(int r=0;r<4;r++){
        int n = mt*16 + quad*4 + r;
        s_h1[n*136 + ft0*16 + c] = (__bf16)sspfast(acc0[r] + bias0);
        s_h1[n*136 + ft1*16 + c] = (__bf16)sspfast(acc1[r] + bias1);
      }
    }
  }
  __syncthreads();

  // GEMM2: W = h1 @ fw2 + fb2, fused v = sum_n W .* (y[nbr]*mask)
  {
    const __bf16* fw2l = fw2tb + layer*F_*F_;
    bf16x8 bw0[4], bw1[4];
    #pragma unroll
    for(int kt=0;kt<4;kt++){
      bw0[kt] = *(const bf16x8*)(fw2l + (ft0*16 + c)*F_ + kt*32 + quad*8);
      bw1[kt] = *(const bf16x8*)(fw2l + (ft1*16 + c)*F_ + kt*32 + quad*8);
    }
    float fb2_0 = fb2g[layer*F_ + ft0*16 + c];
    float fb2_1 = fb2g[layer*F_ + ft1*16 + c];
    float vp0 = 0.0f, vp1 = 0.0f;
    #pragma unroll
    for(int mt=0; mt<4; mt++){
      floatx4 acc0 = {0.f,0.f,0.f,0.f};
      floatx4 acc1 = {0.f,0.f,0.f,0.f};
      #pragma unroll
      for(int kt=0;kt<4;kt++){
        bf16x8 a = *(const bf16x8*)(s_h1 + (mt*16 + c)*136 + kt*32 + quad*8);
        acc0 = __builtin_amdgcn_mfma_f32_16x16x32_bf16(a, bw0[kt], acc0, 0,0,0);
        acc1 = __builtin_amdgcn_mfma_f32_16x16x32_bf16(a, bw1[kt], acc1, 0,0,0);
      }
      // yj directly from global (L2) into registers, mask from LDS broadcast
      float ym0[4], ym1[4];
      #pragma unroll
      for(int r=0;r<4;r++){
        int n = mt*16 + quad*4 + r;
        const float* yr = yws + ((long long)(b*A_ + s_nbr[n]))*F_;
        float msk = s_mask[n];
        ym0[r] = yr[ft0*16 + c] * msk;
        ym1[r] = yr[ft1*16 + c] * msk;
      }
      #pragma unroll
      for(int r=0;r<4;r++){
        vp0 += (acc0[r] + fb2_0) * ym0[r];
        vp1 += (acc1[r] + fb2_1) * ym1[r];
      }
    }
    vp0 += __shfl_xor(vp0, 16); vp0 += __shfl_xor(vp0, 32);
    vp1 += __shfl_xor(vp1, 16); vp1 += __shfl_xor(vp1, 32);
    if(quad == 0){
      vwsb[(long long)m*F_ + ft0*16 + c] = (__bf16)vp0;
      vwsb[(long long)m*F_ + ft1*16 + c] = (__bf16)vp1;
    }
  }
}

// ------------------------------------------------ batched post: t1=ssp(v@W3+b); xn=x+t1@W4+b; y=xn@W1next
__global__ __launch_bounds__(256, 4) void k_post(
    const __bf16* __restrict__ vwsb, float* __restrict__ xws,
    const __bf16* __restrict__ f2owl, const float* __restrict__ f2obl,
    const __bf16* __restrict__ dwl,  const float* __restrict__ dbl,
    const __bf16* __restrict__ in2fnext, float* __restrict__ yws,
    void* __restrict__ dout, const int* __restrict__ flag,
    int has_next, int write_out)
{
  __shared__ __align__(16) unsigned char smem[34816];
  __bf16* s_a = (__bf16*)smem;            // [64][136]
  __bf16* s_b = (__bf16*)(smem + 17408);  // [64][136]
  int t = threadIdx.x;
  int row0 = blockIdx.x*64;
  int lane = t & 63, wid = t >> 6, c = lane & 15, quad = lane >> 4;
  int ft0 = wid, ft1 = wid + 4;
  int isbf = *flag;

  // stage v (already bf16)
  #pragma unroll
  for(int i=0;i<4;i++){
    int ch = t + i*256;
    int row = ch >> 4, col8 = ch & 15;
    *(bf16x8*)(s_a + row*136 + col8*8) =
      *(const bf16x8*)(vwsb + (long long)(row0+row)*F_ + col8*8);
  }
  __syncthreads();

  // GEMM A: t1 = ssp(v @ f2ow + f2ob) -> s_b
  {
    bf16x8 bw0[4], bw1[4];
    #pragma unroll
    for(int kt=0;kt<4;kt++){
      bw0[kt] = *(const bf16x8*)(f2owl + (ft0*16 + c)*F_ + kt*32 + quad*8);
      bw1[kt] = *(const bf16x8*)(f2owl + (ft1*16 + c)*F_ + kt*32 + quad*8);
    }
    float b0 = f2obl[ft0*16 + c], b1 = f2obl[ft1*16 + c];
    #pragma unroll
    for(int mt=0; mt<4; mt++){
      floatx4 acc0 = {0.f,0.f,0.f,0.f};
      floatx4 acc1 = {0.f,0.f,0.f,0.f};
      #pragma unroll
      for(int kt=0;kt<4;kt++){
        bf16x8 a = *(const bf16x8*)(s_a + (mt*16 + c)*136 + kt*32 + quad*8);
        acc0 = __builtin_amdgcn_mfma_f32_16x16x32_bf16(a, bw0[kt], acc0, 0,0,0);
        acc1 = __builtin_amdgcn_mfma_f32_16x16x32_bf16(a, bw1[kt], acc1, 0,0,0);
      }
      #pragma unroll
      for(int r=0;r<4;r++){
        int n = mt*16 + quad*4 + r;
        s_b[n*136 + ft0*16 + c] = (__bf16)sspfast(acc0[r] + b0);
        s_b[n*136 + ft1*16 + c] = (__bf16)sspfast(acc1[r] + b1);
      }
    }
  }
  __syncthreads();

  // GEMM B: xn = x + t1 @ dw + db -> xws (fp32), s_a (bf16), dout (if last)
  {
    bf16x8 bw0[4], bw1[4];
    #pragma unroll
    for(int kt=0;kt<4;kt++){
      bw0[kt] = *(const bf16x8*)(dwl + (ft0*16 + c)*F_ + kt*32 + quad*8);
      bw1[kt] = *(const bf16x8*)(dwl + (ft1*16 + c)*F_ + kt*32 + quad*8);
    }
    float b0 = dbl[ft0*16 + c], b1 = dbl[ft1*16 + c];
    #pragma unroll
    for(int mt=0; mt<4; mt++){
      floatx4 acc0 = {0.f,0.f,0.f,0.f};
      floatx4 acc1 = {0.f,0.f,0.f,0.f};
      #pragma unroll
      for(int kt=0;kt<4;kt++){
        bf16x8 a = *(const bf16x8*)(s_b + (mt*16 + c)*136 + kt*32 + quad*8);
        acc0 = __builtin_amdgcn_mfma_f32_16x16x32_bf16(a, bw0[kt], acc0, 0,0,0);
        acc1 = __builtin_amdgcn_mfma_f32_16x16x32_bf16(a, bw1[kt], acc1, 0,0,0);
      }
      #pragma unroll
      for(int r=0;r<4;r++){
        int n = mt*16 + quad*4 + r;
        long long gi0 = (long long)(row0+n)*F_ + ft0*16 + c;
        long long gi1 = (long long)(row0+n)*F_ + ft1*16 + c;
        float xn0 = xws[gi0] + acc0[r] + b0;
        float xn1 = xws[gi1] + acc1[r] + b1;
        xws[gi0] = xn0; xws[gi1] = xn1;
        s_a[n*136 + ft0*16 + c] = (__bf16)xn0;
        s_a[n*136 + ft1*16 + c] = (__bf16)xn1;
        if(write_out){
          if(isbf){ ((bf16*)dout)[gi0] = __float2bfloat16(xn0);
                    ((bf16*)dout)[gi1] = __float2bfloat16(xn1); }
          else    { ((float*)dout)[gi0] = xn0; ((float*)dout)[gi1] = xn1; }
        }
      }
    }
  }
  if(!has_next) return;
  __syncthreads();

  // GEMM C: y = xn @ in2f(next) -> yws
  {
    bf16x8 bw0[4], bw1[4];
    #pragma unroll
    for(int kt=0;kt<4;kt++){
      bw0[kt] = *(const bf16x8*)(in2fnext + (ft0*16 + c)*F_ + kt*32 + quad*8);
      bw1[kt] = *(const bf16x8*)(in2fnext + (ft1*16 + c)*F_ + kt*32 + quad*8);
    }
    #pragma unroll
    for(int mt=0; mt<4; mt++){
      floatx4 acc0 = {0.f,0.f,0.f,0.f};
      floatx4 acc1 = {0.f,0.f,0.f,0.f};
      #pragma unroll
      for(int kt=0;kt<4;kt++){
        bf16x8 a = *(const bf16x8*)(s_a + (mt*16 + c)*136 + kt*32 + quad*8);
        acc0 = __builtin_amdgcn_mfma_f32_16x16x32_bf16(a, bw0[kt], acc0, 0,0,0);
        acc1 = __builtin_amdgcn_mfma_f32_16x16x32_bf16(a, bw1[kt], acc1, 0,0,0);
      }
      #pragma unroll
      for(int r=0;r<4;r++){
        int n = mt*16 + quad*4 + r;
        yws[(long long)(row0+n)*F_ + ft0*16 + c] = acc0[r];
        yws[(long long)(row0+n)*F_ + ft1*16 + c] = acc1[r];
      }
    }
  }
}

// ------------------------------------------------ launch
extern "C" void kernel_launch(void* const* d_in, const int* in_sizes, int n_in,
                              void* d_out, int out_size, void* d_ws, size_t ws_size,
                              hipStream_t stream){
  const int*  z       = (const int*)d_in[0];
  const void* pos     = d_in[1];
  const void* cell    = d_in[2];
  const void* celloff = d_in[3];
  const int*  nbr     = (const int*)d_in[4];
  const void* mask    = d_in[5];
  const void* emb     = d_in[6];
  const void* fw1     = d_in[7];
  const void* fb1     = d_in[8];
  const void* fw2     = d_in[9];
  const void* fb2     = d_in[10];
  const void* in2f    = d_in[11];
  const void* f2ow    = d_in[12];
  const void* f2ob    = d_in[13];
  const void* dw      = d_in[14];
  const void* db      = d_in[15];

  float* base = (float*)d_ws;
  int*   flag   = (int*)d_ws;
  float* c_emb  = base + 16;                       // 12800
  float* c_fb1  = c_emb + 12800;                   // 384
  float* c_fb2  = c_fb1 + 384;                     // 384
  float* c_f2ob = c_fb2 + 384;                     // 384
  float* c_db   = c_f2ob + 384;                    // 384
  __bf16* fw1tb  = (__bf16*)(c_db + 384);          // 12288 bf16 (6144 fl)
  __bf16* fw2tb  = (__bf16*)(base + 20496);        // 49152 bf16 (24576 fl)
  __bf16* f2owtb = (__bf16*)(base + 45072);
  __bf16* dwtb   = (__bf16*)(base + 69648);
  __bf16* in2ftb = (__bf16*)(base + 94224);
  float* xws  = base + 118800;                     // 1048576
  float* yws  = xws + B_*A_*F_;                    // 1048576
  __bf16* vwsb = (__bf16*)(yws + B_*A_*F_);        // 1048576 bf16 (524288 fl)
  float* rws  = (float*)(yws + B_*A_*F_ + 524288); // 524288  -> total ~13.1 MB

  k_sniff<<<1, 128, 0, stream>>>((const unsigned int*)pos, flag);
  k_prep<<<(223232+255)/256, 256, 0, stream>>>(emb, fb1, fb2, f2ob, db,
                                               fw1, fw2, f2ow, dw, in2f,
                                               c_emb, c_fb1, c_fb2, c_f2ob, c_db,
                                               fw1tb, fw2tb, f2owtb, dwtb, in2ftb, flag);
  k_rdist<<<(B_*A_*NN_+255)/256, 256, 0, stream>>>(pos, cell, celloff, nbr, flag, rws);
  k_embed<<<(B_*A_*F_+255)/256, 256, 0, stream>>>(z, c_emb, xws);
  k_ygemm<<<(B_*A_)/64, 256, 0, stream>>>(xws, in2ftb, yws);

  for(int l=0;l<L_;l++){
    k_atom<<<B_*A_, 256, 0, stream>>>(yws, rws, nbr, mask,
                                      fw1tb, c_fb1, fw2tb, c_fb2,
                                      flag, vwsb, l);
    k_post<<<(B_*A_)/64, 256, 0, stream>>>(vwsb, xws,
                                           f2owtb + l*F_*F_, c_f2ob + l*F_,
                                           dwtb + l*F_*F_,  c_db + l*F_,
                                           in2ftb + (l < L_-1 ? (l+1)*F_*F_ : 0), yws,
                                           d_out, flag,
                                           (l < L_-1) ? 1 : 0, (l == L_-1) ? 1 : 0);
  }
}